// Round 14
// baseline (784.751 us; speedup 1.0000x reference)
//
#include <hip/hip_runtime.h>
#include <hip/hip_fp16.h>
#include <hip/hip_cooperative_groups.h>

namespace cg = cooperative_groups;

#define N_NODES 100000
#define N_EDGES 3200000
#define QCH 32
#define QP 16                   // half2 pairs per node
#define DT_C 0.1f

#define NCHUNK 128
#define CHUNK_E (N_EDGES / NCHUNK)   // 25000
#define HALF_NODES 50000
#define WORDS_HALF 12500             // HALF_NODES/4 (u8-packed u32 words)
#define WORDS_TOT 25000              // N_NODES/4

#define COOP_BLOCKS 2048             // 8 blocks/CU * 256 CUs -> 32 waves/CU
#define COOP_THREADS 256

// ---- degree via contention-free LDS histogram (no global atomics) ----
__global__ __launch_bounds__(256) void hist_kernel(const int* __restrict__ src,
                                                   unsigned int* __restrict__ part) {
    __shared__ unsigned int h[WORDS_HALF];     // 50 KB
    int tid = threadIdx.x;
    int chunk = blockIdx.x >> 1;
    int rh = blockIdx.x & 1;
    int r0 = rh * HALF_NODES;
    for (int i = tid; i < WORDS_HALF; i += 256) h[i] = 0u;
    __syncthreads();
    int e0 = chunk * CHUNK_E;
    for (int e = e0 + tid; e < e0 + CHUNK_E; e += 256) {
        int n = src[e] - r0;
        if ((unsigned)n < HALF_NODES)
            atomicAdd(&h[n >> 2], 1u << (8 * (n & 3)));   // byte-packed count
    }
    __syncthreads();
    unsigned int* dstp = part + (size_t)chunk * WORDS_TOT + rh * WORDS_HALF;
    for (int i = tid; i < WORDS_HALF; i += 256) dstp[i] = h[i];
}

// ---- fused cooperative kernel: {zero+degsum} -> edge scatter -> finalize ----
// 8 blocks/CU co-resident (launch_bounds 2nd arg = blocks/CU for 256-thr blocks)
__global__ __launch_bounds__(COOP_THREADS, 8) void fused_kernel(
        const float2* __restrict__ f2,
        const float4* __restrict__ coll4,
        const float4* __restrict__ srct4,
        const float* __restrict__ w,
        const int* __restrict__ src,
        const int* __restrict__ dst,
        const unsigned int* __restrict__ part,
        float* __restrict__ deg,
        __half2* __restrict__ trans,
        float4* __restrict__ out) {
    cg::grid_group grid = cg::this_grid();
    int tid = blockIdx.x * blockDim.x + threadIdx.x;
    int nthr = gridDim.x * blockDim.x;

    // Phase A1: zero trans (6.4 MB as 400K float4)
    float4* t4 = (float4*)trans;
    for (int i = tid; i < (N_NODES * QCH) / 8; i += nthr)
        t4[i] = make_float4(0.0f, 0.0f, 0.0f, 0.0f);
    // Phase A2: sum byte-packed partials -> float out-degree
    for (int wd = tid; wd < WORDS_TOT; wd += nthr) {
        unsigned int s0 = 0, s1 = 0, s2 = 0, s3 = 0;
#pragma unroll 8
        for (int c = 0; c < NCHUNK; ++c) {
            unsigned int v = part[(size_t)c * WORDS_TOT + wd];
            s0 += v & 255u;
            s1 += (v >> 8) & 255u;
            s2 += (v >> 16) & 255u;
            s3 += v >> 24;
        }
        *(float4*)(deg + 4 * wd) =
            make_float4((float)s0, (float)s1, (float)s2, (float)s3);
    }
    grid.sync();

    // Phase B: edge scatter (proven arithmetic; stride multiple of 16 keeps
    // the 16-lane-per-edge coalescing pattern)
    long long total = (long long)N_EDGES * QP;
    for (long long t = tid; t < total; t += nthr) {
        int e = (int)(t >> 4);
        int qp = (int)(t & 15);
        int s = src[e];
        int d = dst[e];
        float coef = w[e] / fmaxf(deg[s], 1.0f);
        float2 fs = f2[s * QP + qp];
        float2 fd = f2[d * QP + qp];
        float xi0 = (75.0f / 31.0f) * (float)(2 * qp);
        float xi1 = (75.0f / 31.0f) * (float)(2 * qp + 1);
        float m0 = coef * xi0 * (fmaxf(fd.x, 0.0f) - fmaxf(fs.x, 0.0f));
        float m1 = coef * xi1 * (fmaxf(fd.y, 0.0f) - fmaxf(fs.y, 0.0f));
        unsafeAtomicAdd(&trans[s * QP + qp], __floats2half2_rn(m0, m1));
        unsafeAtomicAdd(&trans[d * QP + qp], __floats2half2_rn(-m0, -m1));
    }
    grid.sync();

    // Phase C: finalize (float4)
    const float4* f4v = (const float4*)f2;
    int n4 = N_NODES * QCH / 4;
    for (int i = tid; i < n4; i += nthr) {
        float2 t0 = __half22float2(trans[2 * i]);
        float2 t1 = __half22float2(trans[2 * i + 1]);
        float4 fr = f4v[i];
        float4 cl = coll4[i];
        float4 st = srct4[i];
        float4 o;
        o.x = fmaxf(fmaxf(fr.x, 0.0f) - DT_C * (t0.x - cl.x - st.x), 0.0f);
        o.y = fmaxf(fmaxf(fr.y, 0.0f) - DT_C * (t0.y - cl.y - st.y), 0.0f);
        o.z = fmaxf(fmaxf(fr.z, 0.0f) - DT_C * (t1.x - cl.z - st.z), 0.0f);
        o.w = fmaxf(fmaxf(fr.w, 0.0f) - DT_C * (t1.y - cl.w - st.w), 0.0f);
        out[i] = o;
    }
}

// ---------------- fallback kernels (r12 proven path) ----------------

__global__ __launch_bounds__(256) void degsum_kernel(
        const unsigned int* __restrict__ part, float* __restrict__ deg) {
    int wd = blockIdx.x * 256 + threadIdx.x;
    if (wd >= WORDS_TOT) return;
    unsigned int s0 = 0, s1 = 0, s2 = 0, s3 = 0;
#pragma unroll 8
    for (int i = 0; i < NCHUNK; ++i) {
        unsigned int v = part[(size_t)i * WORDS_TOT + wd];
        s0 += v & 255u;
        s1 += (v >> 8) & 255u;
        s2 += (v >> 16) & 255u;
        s3 += v >> 24;
    }
    *(float4*)(deg + 4 * wd) =
        make_float4((float)s0, (float)s1, (float)s2, (float)s3);
}

__global__ void edge_kernel_h2(const float2* __restrict__ f2,
                               const float* __restrict__ w,
                               const int* __restrict__ src,
                               const int* __restrict__ dst,
                               const float* __restrict__ deg,
                               __half2* __restrict__ trans, int E) {
    long long t = (long long)blockIdx.x * blockDim.x + threadIdx.x;
    int e = (int)(t >> 4);
    int qp = (int)(t & 15);
    if (e >= E) return;
    int s = src[e];
    int d = dst[e];
    float coef = w[e] / fmaxf(deg[s], 1.0f);
    float2 fs = f2[s * QP + qp];
    float2 fd = f2[d * QP + qp];
    float xi0 = (75.0f / 31.0f) * (float)(2 * qp);
    float xi1 = (75.0f / 31.0f) * (float)(2 * qp + 1);
    float m0 = coef * xi0 * (fmaxf(fd.x, 0.0f) - fmaxf(fs.x, 0.0f));
    float m1 = coef * xi1 * (fmaxf(fd.y, 0.0f) - fmaxf(fs.y, 0.0f));
    unsafeAtomicAdd(&trans[s * QP + qp], __floats2half2_rn(m0, m1));
    unsafeAtomicAdd(&trans[d * QP + qp], __floats2half2_rn(-m0, -m1));
}

__global__ void final_f4(const float4* __restrict__ fdist,
                         const float4* __restrict__ coll,
                         const float4* __restrict__ srct,
                         const __half2* __restrict__ trans,
                         float4* __restrict__ out, int n4) {
    int i = blockIdx.x * blockDim.x + threadIdx.x;
    if (i >= n4) return;
    float2 t0 = __half22float2(trans[2 * i]);
    float2 t1 = __half22float2(trans[2 * i + 1]);
    float4 fr = fdist[i];
    float4 cl = coll[i];
    float4 st = srct[i];
    float4 o;
    o.x = fmaxf(fmaxf(fr.x, 0.0f) - DT_C * (t0.x - cl.x - st.x), 0.0f);
    o.y = fmaxf(fmaxf(fr.y, 0.0f) - DT_C * (t0.y - cl.y - st.y), 0.0f);
    o.z = fmaxf(fmaxf(fr.z, 0.0f) - DT_C * (t1.x - cl.z - st.z), 0.0f);
    o.w = fmaxf(fmaxf(fr.w, 0.0f) - DT_C * (t1.y - cl.w - st.w), 0.0f);
    out[i] = o;
}

__global__ void deg_kernel_f(const int* __restrict__ src,
                             float* __restrict__ deg, int E) {
    int e = blockIdx.x * blockDim.x + threadIdx.x;
    if (e < E) atomicAdd(&deg[src[e]], 1.0f);
}

// ---------------- launch ----------------

extern "C" void kernel_launch(void* const* d_in, const int* in_sizes, int n_in,
                              void* d_out, int out_size, void* d_ws, size_t ws_size,
                              hipStream_t stream) {
    const float* f    = (const float*)d_in[0];  // [N, Q]
    const float* coll = (const float*)d_in[1];  // [N, Q]
    const float* srct = (const float*)d_in[2];  // [N, Q]
    const float* w    = (const float*)d_in[3];  // [E]
    const int*   src  = (const int*)d_in[4];    // [E]
    const int*   dst  = (const int*)d_in[5];    // [E]
    float* out = (float*)d_out;                 // [N, Q]

    const int N = N_NODES;
    const int E = N_EDGES;

    const size_t TRANS_B = (size_t)N * QP * sizeof(__half2);
    const size_t DEG_B   = (size_t)N * sizeof(float);
    const size_t PART_B  = (size_t)NCHUNK * WORDS_TOT * sizeof(unsigned int);

    __half2* trans = (__half2*)d_ws;
    float*   deg   = (float*)((char*)d_ws + TRANS_B);
    unsigned int* part = (unsigned int*)((char*)deg + DEG_B);

    bool have_part = ws_size >= TRANS_B + DEG_B + PART_B;

    if (have_part) {
        hist_kernel<<<2 * NCHUNK, 256, 0, stream>>>(src, part);

        const float2* f2p   = (const float2*)f;
        const float4* coll4 = (const float4*)coll;
        const float4* srct4 = (const float4*)srct;
        float4* out4 = (float4*)out;
        void* args[] = {(void*)&f2p, (void*)&coll4, (void*)&srct4,
                        (void*)&w, (void*)&src, (void*)&dst,
                        (void*)&part, (void*)&deg, (void*)&trans,
                        (void*)&out4};
        hipError_t err = hipLaunchCooperativeKernel(
            (const void*)fused_kernel, dim3(COOP_BLOCKS), dim3(COOP_THREADS),
            args, 0, stream);
        if (err == hipSuccess) return;

        // cooperative launch unavailable -> proven r12 sequence
        hipMemsetAsync(trans, 0, TRANS_B, stream);
        degsum_kernel<<<(WORDS_TOT + 255) / 256, 256, 0, stream>>>(part, deg);
    } else {
        hipMemsetAsync(trans, 0, TRANS_B, stream);
        hipMemsetAsync(deg, 0, DEG_B, stream);
        deg_kernel_f<<<(E + 255) / 256, 256, 0, stream>>>(src, deg, E);
    }

    long long total = (long long)E * QP;
    int blocks = (int)((total + 255) / 256);
    edge_kernel_h2<<<blocks, 256, 0, stream>>>((const float2*)f, w, src, dst,
                                               deg, trans, E);

    int n4 = N * QCH / 4;
    final_f4<<<(n4 + 255) / 256, 256, 0, stream>>>((const float4*)f,
                                                   (const float4*)coll,
                                                   (const float4*)srct,
                                                   trans, (float4*)out, n4);
}

// Round 15
// 358.303 us; speedup vs baseline: 2.1902x; 2.1902x over previous
//
#include <hip/hip_runtime.h>
#include <hip/hip_fp16.h>

#define N_NODES 100000
#define N_EDGES 3200000
#define QCH 32
#define QP 16                   // half2 pairs per node
#define DT_C 0.1f

#define NCHUNK 256
#define CHUNK_E (N_EDGES / NCHUNK)   // 12500
#define HALF_NODES 50000
#define WORDS_HALF 12500             // HALF_NODES/4 (u8-packed u32 words)
#define WORDS_TOT 25000              // N_NODES/4

#define TRANS_F4 400000              // trans = 6.4 MB = 400000 float4
#define HIST_BLOCKS (2 * NCHUNK)     // 512
#define ZSLICE 782                   // ceil(400000/512)

// ---- degree histogram (contention-free, no global atomics) + fused
//      trans-zero (saves the memset dispatch; completes before edge) ----
__global__ __launch_bounds__(256) void hist_kernel(const int* __restrict__ src,
                                                   unsigned int* __restrict__ part,
                                                   float4* __restrict__ transz) {
    int tid = threadIdx.x;
    // zero this block's slice of trans
    int zbase = blockIdx.x * ZSLICE;
    for (int i = tid; i < ZSLICE; i += 256) {
        int idx = zbase + i;
        if (idx < TRANS_F4) transz[idx] = make_float4(0.f, 0.f, 0.f, 0.f);
    }
    __shared__ unsigned int h[WORDS_HALF];     // 50 KB
    int chunk = blockIdx.x >> 1;
    int rh = blockIdx.x & 1;
    int r0 = rh * HALF_NODES;
    for (int i = tid; i < WORDS_HALF; i += 256) h[i] = 0u;
    __syncthreads();
    int e0 = chunk * CHUNK_E;
    for (int e = e0 + tid; e < e0 + CHUNK_E; e += 256) {
        int n = src[e] - r0;
        if ((unsigned)n < HALF_NODES)
            atomicAdd(&h[n >> 2], 1u << (8 * (n & 3)));   // byte-packed count
    }
    __syncthreads();
    unsigned int* dstp = part + (size_t)chunk * WORDS_TOT + rh * WORDS_HALF;
    for (int i = tid; i < WORDS_HALF; i += 256) dstp[i] = h[i];
}

// Sum the byte-packed partials -> float out-degree. 98 blocks, coalesced.
__global__ __launch_bounds__(256) void degsum_kernel(
        const unsigned int* __restrict__ part, float* __restrict__ deg) {
    int wd = blockIdx.x * 256 + threadIdx.x;
    if (wd >= WORDS_TOT) return;
    unsigned int s0 = 0, s1 = 0, s2 = 0, s3 = 0;
#pragma unroll 8
    for (int i = 0; i < NCHUNK; ++i) {
        unsigned int v = part[(size_t)i * WORDS_TOT + wd];
        s0 += v & 255u;
        s1 += (v >> 8) & 255u;
        s2 += (v >> 16) & 255u;
        s3 += v >> 24;
    }
    *(float4*)(deg + 4 * wd) =
        make_float4((float)s0, (float)s1, (float)s2, (float)s3);
}

// Edge scatter (proven r2 kernel): one thread per (edge, q-pair); one 4B
// pk_f16 atomic per endpoint. At the atomic write-through wall
// (400 MB @ ~1.29 TB/s) — measured structural floor for this op.
__global__ void edge_kernel_h2(const float2* __restrict__ f2,
                               const float* __restrict__ w,
                               const int* __restrict__ src,
                               const int* __restrict__ dst,
                               const float* __restrict__ deg,
                               __half2* __restrict__ trans, int E) {
    long long t = (long long)blockIdx.x * blockDim.x + threadIdx.x;
    int e = (int)(t >> 4);
    int qp = (int)(t & 15);
    if (e >= E) return;
    int s = src[e];
    int d = dst[e];
    float coef = w[e] / fmaxf(deg[s], 1.0f);
    float2 fs = f2[s * QP + qp];
    float2 fd = f2[d * QP + qp];
    float xi0 = (75.0f / 31.0f) * (float)(2 * qp);
    float xi1 = (75.0f / 31.0f) * (float)(2 * qp + 1);
    float m0 = coef * xi0 * (fmaxf(fd.x, 0.0f) - fmaxf(fs.x, 0.0f));
    float m1 = coef * xi1 * (fmaxf(fd.y, 0.0f) - fmaxf(fs.y, 0.0f));
    unsafeAtomicAdd(&trans[s * QP + qp], __floats2half2_rn(m0, m1));   // outflow
    unsafeAtomicAdd(&trans[d * QP + qp], __floats2half2_rn(-m0, -m1)); // -inflow
}

// Finalize, float4-vectorized: one thread per 4 channels.
__global__ void final_f4(const float4* __restrict__ fdist,
                         const float4* __restrict__ coll,
                         const float4* __restrict__ srct,
                         const __half2* __restrict__ trans,
                         float4* __restrict__ out, int n4) {
    int i = blockIdx.x * blockDim.x + threadIdx.x;
    if (i >= n4) return;
    float2 t0 = __half22float2(trans[2 * i]);
    float2 t1 = __half22float2(trans[2 * i + 1]);
    float4 fr = fdist[i];
    float4 cl = coll[i];
    float4 st = srct[i];
    float4 o;
    o.x = fmaxf(fmaxf(fr.x, 0.0f) - DT_C * (t0.x - cl.x - st.x), 0.0f);
    o.y = fmaxf(fmaxf(fr.y, 0.0f) - DT_C * (t0.y - cl.y - st.y), 0.0f);
    o.z = fmaxf(fmaxf(fr.z, 0.0f) - DT_C * (t1.x - cl.z - st.z), 0.0f);
    o.w = fmaxf(fmaxf(fr.w, 0.0f) - DT_C * (t1.y - cl.w - st.w), 0.0f);
    out[i] = o;
}

// fallback deg (global atomics) if ws ever too small for partials
__global__ void deg_kernel_f(const int* __restrict__ src,
                             float* __restrict__ deg, int E) {
    int e = blockIdx.x * blockDim.x + threadIdx.x;
    if (e < E) atomicAdd(&deg[src[e]], 1.0f);
}

extern "C" void kernel_launch(void* const* d_in, const int* in_sizes, int n_in,
                              void* d_out, int out_size, void* d_ws, size_t ws_size,
                              hipStream_t stream) {
    const float* f    = (const float*)d_in[0];  // [N, Q]
    const float* coll = (const float*)d_in[1];  // [N, Q]
    const float* srct = (const float*)d_in[2];  // [N, Q]
    const float* w    = (const float*)d_in[3];  // [E]
    const int*   src  = (const int*)d_in[4];    // [E]
    const int*   dst  = (const int*)d_in[5];    // [E]
    float* out = (float*)d_out;                 // [N, Q]

    const int N = N_NODES;
    const int E = N_EDGES;

    // ws: half2 trans[N*QP] (6.4MB) | float deg[N] (0.4MB)
    //     | u32 part[NCHUNK*WORDS_TOT] (25.6MB)
    const size_t TRANS_B = (size_t)N * QP * sizeof(__half2);
    const size_t DEG_B   = (size_t)N * sizeof(float);
    const size_t PART_B  = (size_t)NCHUNK * WORDS_TOT * sizeof(unsigned int);

    __half2* trans = (__half2*)d_ws;
    float*   deg   = (float*)((char*)d_ws + TRANS_B);
    unsigned int* part = (unsigned int*)((char*)deg + DEG_B);

    if (ws_size >= TRANS_B + DEG_B + PART_B) {
        // hist also zeros trans (fused) — completes before edge dispatch
        hist_kernel<<<HIST_BLOCKS, 256, 0, stream>>>(src, part, (float4*)trans);
        degsum_kernel<<<(WORDS_TOT + 255) / 256, 256, 0, stream>>>(part, deg);
    } else {
        hipMemsetAsync(trans, 0, TRANS_B, stream);
        hipMemsetAsync(deg, 0, DEG_B, stream);
        deg_kernel_f<<<(E + 255) / 256, 256, 0, stream>>>(src, deg, E);
    }

    long long total = (long long)E * QP;
    int blocks = (int)((total + 255) / 256);
    edge_kernel_h2<<<blocks, 256, 0, stream>>>((const float2*)f, w, src, dst,
                                               deg, trans, E);

    int n4 = N * QCH / 4;
    final_f4<<<(n4 + 255) / 256, 256, 0, stream>>>((const float4*)f,
                                                   (const float4*)coll,
                                                   (const float4*)srct,
                                                   trans, (float4*)out, n4);
}